// Round 5
// baseline (195.447 us; speedup 1.0000x reference)
//
#include <hip/hip_runtime.h>

// Causal single-head attention, B=4, S=4096, D=128, fp32 in/out.
// R5 (= R4 + compile fix): S^T = K*Q^T orientation (per-lane softmax rows:
// 2-shfl reductions, scalar m/l, in-register P transpose via shfl). Single
// 32KB LDS tile buffer + register prefetch -> 4 blocks/CU. prep/merge 2048
// blocks. pkbf now packs bf16 pair via f2bf (no __hip_bfloat162 bit_cast).

#define B_   4
#define S_   4096
#define D_   128
#define BM   64
#define BN   64
#define NT_  (S_ / BM)      // 64 q-tiles per batch
#define RMAX 4
#define BLOB_SHORTS 16384   // 32 KB per (b,kt): [K img 16KB][V^T img 16KB]

typedef __attribute__((ext_vector_type(8))) short bf16x8;
typedef __attribute__((ext_vector_type(4))) float f32x4;

__device__ __forceinline__ short f2bf(float x) {
    unsigned u = __builtin_bit_cast(unsigned, x);
    unsigned r = (u + 0x7fffu + ((u >> 16) & 1u)) >> 16;
    return (short)r;
}
__device__ __forceinline__ float ex2(float x) { return __builtin_amdgcn_exp2f(x); }
__device__ __forceinline__ unsigned pkbf(float lo, float hi) {
    return (unsigned)(unsigned short)f2bf(lo) | ((unsigned)(unsigned short)f2bf(hi) << 16);
}

// ---------------- prep: 2048 blocks ---------------------------------------
// id<1024: QK quarter-rows. id>=1024: V^T quarter-d via LDS transpose.
// K image: row n (64) x 16 granules of 8 bf16; source granule G at
//   p = (G&8) | ((G&7) ^ (n&7)).
// V image: row d (128) x 8 granules; source granule G (= k-octet) at
//   p = G ^ (d&7); granule holds V[kt*64+G*8+i][d], i=0..7.
__global__ __launch_bounds__(256) void prep(const float* __restrict__ Qg,
                                            const float* __restrict__ Kg,
                                            const float* __restrict__ Vg,
                                            short* __restrict__ Qbf,
                                            short* __restrict__ KV)
{
    __shared__ short vt[64][40];
    const int id  = blockIdx.x;
    const int tid = threadIdx.x;
    const float SC = 0.12751740f;   // log2(e)/sqrt(128)

    if (id < 1024) {
        const int b = id & 3, tile = (id >> 2) & 63, q4 = id >> 8;
        const int n = q4 * 16 + (tid >> 4);       // row within tile
        const int G = tid & 15;                   // 8-col granule
        const size_t rowoff = ((size_t)b * S_ + (size_t)tile * 64 + n) * D_ + G * 8;
        short* blob = KV + (size_t)(b * NT_ + tile) * BLOB_SHORTS;
        {
            float4 a = *reinterpret_cast<const float4*>(Qg + rowoff);
            float4 c = *reinterpret_cast<const float4*>(Qg + rowoff + 4);
            bf16x8 v;
            v[0] = f2bf(a.x * SC); v[1] = f2bf(a.y * SC); v[2] = f2bf(a.z * SC); v[3] = f2bf(a.w * SC);
            v[4] = f2bf(c.x * SC); v[5] = f2bf(c.y * SC); v[6] = f2bf(c.z * SC); v[7] = f2bf(c.w * SC);
            *reinterpret_cast<bf16x8*>(Qbf + rowoff) = v;
        }
        {
            float4 a = *reinterpret_cast<const float4*>(Kg + rowoff);
            float4 c = *reinterpret_cast<const float4*>(Kg + rowoff + 4);
            bf16x8 v;
            v[0] = f2bf(a.x); v[1] = f2bf(a.y); v[2] = f2bf(a.z); v[3] = f2bf(a.w);
            v[4] = f2bf(c.x); v[5] = f2bf(c.y); v[6] = f2bf(c.z); v[7] = f2bf(c.w);
            const int p = (G & 8) | ((G & 7) ^ (n & 7));
            *reinterpret_cast<bf16x8*>(blob + n * 128 + p * 8) = v;
        }
    } else {
        const int u = id - 1024;
        const int b = u & 3, tile = (u >> 2) & 63, dq = u >> 8;  // d-quarter
        short* blob = KV + (size_t)(b * NT_ + tile) * BLOB_SHORTS;
        {   // stage V[64][dq*32..+32) -> vt bf16
            const int n = tid >> 2, c8 = tid & 3;   // 8 cols each
            const size_t off = ((size_t)b * S_ + (size_t)tile * 64 + n) * D_ + dq * 32 + c8 * 8;
            float4 a = *reinterpret_cast<const float4*>(Vg + off);
            float4 c = *reinterpret_cast<const float4*>(Vg + off + 4);
            bf16x8 v;
            v[0] = f2bf(a.x); v[1] = f2bf(a.y); v[2] = f2bf(a.z); v[3] = f2bf(a.w);
            v[4] = f2bf(c.x); v[5] = f2bf(c.y); v[6] = f2bf(c.z); v[7] = f2bf(c.w);
            *reinterpret_cast<bf16x8*>(&vt[n][c8 * 8]) = v;
        }
        __syncthreads();
        {   // transpose out: thread = (dl 0..31, G 0..7)
            const int dl = tid >> 3, G = tid & 7;
            const int d  = dq * 32 + dl;
            bf16x8 g;
#pragma unroll
            for (int i = 0; i < 8; ++i) g[i] = vt[G * 8 + i][dl];
            const int p = G ^ (d & 7);
            *reinterpret_cast<bf16x8*>(blob + 8192 + d * 64 + p * 8) = g;
        }
    }
}

// ---------------- fa_fwd ---------------------------------------------------
template<bool SPLIT>
__global__ __launch_bounds__(256, 4) void fa_fwd(const short* __restrict__ Qbf,
                                                 const short* __restrict__ KV,
                                                 float* __restrict__ Og,
                                                 float* __restrict__ Op,
                                                 float* __restrict__ Ml,
                                                 int R)
{
    __shared__ short lkv[BLOB_SHORTS];   // single 32 KB tile buffer

    const int tid  = threadIdx.x;
    const int wv   = tid >> 6;
    const int lane = tid & 63;
    const int m    = lane & 15;
    const int quad = lane >> 4;
    const int m7   = m & 7;

    int batch, t, lo, hi, chunk_id;
    {
        const int id = blockIdx.x;
        batch = id & 3;
        if (SPLIT) {
            int u = id >> 2;
            int tt = u / R;
            int r  = u - tt * R;
            t  = NT_ - 1 - tt;                 // heavy q-tiles dispatch first
            lo = r * (t + 1) / R;
            hi = (r + 1) * (t + 1) / R;
            chunk_id = (batch * NT_ + t) * R + r;
            if (lo >= hi) return;              // block-uniform, before barriers
        } else {
            t  = NT_ - 1 - (id >> 2);
            lo = 0; hi = t + 1; chunk_id = 0;
        }
    }

    // Q fragments (pre-scaled bf16): lane&15 = q-row, quad*8+j = d
    bf16x8 qf[4];
    {
        const short* qp = Qbf + ((size_t)batch * S_ + (size_t)t * BM + wv * 16 + m) * D_ + quad * 8;
#pragma unroll
        for (int c = 0; c < 4; ++c)
            qf[c] = *reinterpret_cast<const bf16x8*>(qp + c * 32);
    }

    f32x4 acc[8];
#pragma unroll
    for (int i = 0; i < 8; ++i) acc[i] = (f32x4){0.f, 0.f, 0.f, 0.f};
    float mrun = -__builtin_inff(), lrun = 0.f;   // per-lane: q-row = m

    const size_t tilebase = (size_t)batch * NT_ * BLOB_SHORTS;
    int4 pfr[8];
#define LOADR(KT) do {                                                        \
        const short* g_ = KV + tilebase + (size_t)(KT) * BLOB_SHORTS + tid * 8;\
        _Pragma("unroll")                                                     \
        for (int c_ = 0; c_ < 8; ++c_)                                        \
            pfr[c_] = *reinterpret_cast<const int4*>(g_ + c_ * 2048);         \
    } while (0)

    LOADR(lo);

    for (int kt = lo; kt < hi; ++kt) {
        __syncthreads();                       // readers of lkv (tile kt-1) done
        {
            short* l_ = lkv + tid * 8;
#pragma unroll
            for (int c_ = 0; c_ < 8; ++c_)
                *reinterpret_cast<int4*>(l_ + c_ * 2048) = pfr[c_];
        }
        __syncthreads();                       // tile kt visible
        if (kt + 1 < hi) LOADR(kt + 1);        // overlaps compute below

        const short* lk = lkv;
        const short* lv = lkv + 8192;

        // ---- S^T = K * Q^T : st[nt] rows k-local=quad*4+r, col q=m
        f32x4 st[4];
#pragma unroll
        for (int nt = 0; nt < 4; ++nt) st[nt] = (f32x4){0.f, 0.f, 0.f, 0.f};
#pragma unroll
        for (int c = 0; c < 4; ++c) {
            const int p = ((c >> 1) * 8) | ((((c & 1) * 4) | quad) ^ m7);
#pragma unroll
            for (int nt = 0; nt < 4; ++nt) {
                bf16x8 kf = *reinterpret_cast<const bf16x8*>(lk + nt * 2048 + m * 128 + p * 8);
                st[nt] = __builtin_amdgcn_mfma_f32_16x16x32_bf16(kf, qf[c], st[nt], 0, 0, 0);
            }
        }

        // ---- causal mask (diagonal tile only): mask k > q
        if (kt == t) {
            const int qloc = wv * 16 + m;
#pragma unroll
            for (int nt = 0; nt < 4; ++nt)
#pragma unroll
                for (int r = 0; r < 4; ++r)
                    if (nt * 16 + quad * 4 + r > qloc) st[nt][r] = -__builtin_inff();
        }

        // ---- online softmax: row = m, fully per-lane + 2 shfl
        float mx = -__builtin_inff();
#pragma unroll
        for (int nt = 0; nt < 4; ++nt)
#pragma unroll
            for (int r = 0; r < 4; ++r) mx = fmaxf(mx, st[nt][r]);
        mx = fmaxf(mx, __shfl_xor(mx, 16));
        mx = fmaxf(mx, __shfl_xor(mx, 32));
        const float mnew = fmaxf(mrun, mx);
        const float al   = ex2(mrun - mnew);
        mrun = mnew;
        float sum = 0.f;
#pragma unroll
        for (int nt = 0; nt < 4; ++nt)
#pragma unroll
            for (int r = 0; r < 4; ++r) {
                float pv = ex2(st[nt][r] - mnew);
                st[nt][r] = pv;
                sum += pv;
            }
        sum += __shfl_xor(sum, 16);
        sum += __shfl_xor(sum, 32);
        lrun = lrun * al + sum;
#pragma unroll
        for (int r = 0; r < 4; ++r) {
            float alq = __shfl(al, quad * 4 + r);   // al for q-row quad*4+r
#pragma unroll
            for (int ct = 0; ct < 8; ++ct) acc[ct][r] *= alq;
        }

        // ---- P transpose in-register: pk[nt*2+rp] = (P[m][..2rp], ..2rp+1)
        unsigned pk[8];
#pragma unroll
        for (int nt = 0; nt < 4; ++nt) {
            pk[nt * 2]     = pkbf(st[nt][0], st[nt][1]);
            pk[nt * 2 + 1] = pkbf(st[nt][2], st[nt][3]);
        }
        const int srcA = ((quad & 1) << 5) + m;   // lane 2*(quad&1)*16 + m
        const int srcB = srcA + 16;
        const bool loq = quad < 2;

        // ---- PV: O[16 q][128 d] += P[16][64] * V[64][128]
#pragma unroll
        for (int ks = 0; ks < 2; ++ks) {
            unsigned w0a = __shfl((int)pk[4 * ks + 0], srcA);
            unsigned w0b = __shfl((int)pk[4 * ks + 2], srcA);
            unsigned w1a = __shfl((int)pk[4 * ks + 1], srcA);
            unsigned w1b = __shfl((int)pk[4 * ks + 3], srcA);
            unsigned w2a = __shfl((int)pk[4 * ks + 0], srcB);
            unsigned w2b = __shfl((int)pk[4 * ks + 2], srcB);
            unsigned w3a = __shfl((int)pk[4 * ks + 1], srcB);
            unsigned w3b = __shfl((int)pk[4 * ks + 3], srcB);
            int4 wi;
            wi.x = (int)(loq ? w0a : w0b);
            wi.y = (int)(loq ? w1a : w1b);
            wi.z = (int)(loq ? w2a : w2b);
            wi.w = (int)(loq ? w3a : w3b);
            bf16x8 pf = __builtin_bit_cast(bf16x8, wi);
            const int p = (ks * 4 + quad) ^ m7;
#pragma unroll
            for (int ct = 0; ct < 8; ++ct) {
                bf16x8 vf = *reinterpret_cast<const bf16x8*>(lv + ct * 1024 + m * 64 + p * 8);
                acc[ct] = __builtin_amdgcn_mfma_f32_16x16x32_bf16(pf, vf, acc[ct], 0, 0, 0);
            }
        }
    }
#undef LOADR

    const int row0 = wv * 16 + quad * 4;
    if (SPLIT) {
        float* ob = Op + (size_t)chunk_id * (BM * D_);
#pragma unroll
        for (int r = 0; r < 4; ++r)
#pragma unroll
            for (int ct = 0; ct < 8; ++ct)
                ob[(row0 + r) * D_ + ct * 16 + m] = acc[ct][r];
        if (lane < 16) {
            float* mlb = Ml + (size_t)chunk_id * (BM * 2) + (wv * 16 + lane) * 2;
            mlb[0] = mrun;
            mlb[1] = lrun;
        }
    } else {
        const float inv = 1.0f / lrun;
        const size_t obase = ((size_t)batch * S_ + (size_t)t * BM + row0) * D_;
#pragma unroll
        for (int r = 0; r < 4; ++r) {
            float invq = __shfl(inv, quad * 4 + r);
#pragma unroll
            for (int ct = 0; ct < 8; ++ct)
                Og[obase + (size_t)r * D_ + ct * 16 + m] = acc[ct][r] * invq;
        }
    }
}

// ---------------- merge: 2048 blocks, 8 rows each --------------------------
template<int RR>
__global__ __launch_bounds__(256) void fa_merge(const float* __restrict__ Op,
                                                const float* __restrict__ Ml,
                                                float* __restrict__ Og)
{
    const int x   = blockIdx.x;
    const int btq = x >> 3;                 // b*NT + t
    const int oct = x & 7;
    const int t   = btq & (NT_ - 1);
    const int row = oct * 8 + (threadIdx.x >> 5);
    const int cg  = threadIdx.x & 31;       // 4 floats per thread
    const size_t cbase = (size_t)btq * RR;

    float mg = -__builtin_inff();
#pragma unroll
    for (int r = 0; r < RR; ++r) {
        int lo = r * (t + 1) / RR, hi = (r + 1) * (t + 1) / RR;
        if (lo < hi) mg = fmaxf(mg, Ml[(cbase + r) * (BM * 2) + row * 2]);
    }
    float l = 0.f;
    f32x4 a = (f32x4){0.f, 0.f, 0.f, 0.f};
#pragma unroll
    for (int r = 0; r < RR; ++r) {
        int lo = r * (t + 1) / RR, hi = (r + 1) * (t + 1) / RR;
        if (lo >= hi) continue;
        float mr = Ml[(cbase + r) * (BM * 2) + row * 2];
        float lr = Ml[(cbase + r) * (BM * 2) + row * 2 + 1];
        float w  = ex2(mr - mg);
        l += lr * w;
        a += w * *reinterpret_cast<const f32x4*>(Op + (cbase + r) * (BM * D_) + row * D_ + cg * 4);
    }
    *reinterpret_cast<f32x4*>(Og + (size_t)btq * (BM * D_) + row * D_ + cg * 4) = a * (1.0f / l);
}

extern "C" void kernel_launch(void* const* d_in, const int* in_sizes, int n_in,
                              void* d_out, int out_size, void* d_ws, size_t ws_size,
                              hipStream_t stream) {
    const float* q = (const float*)d_in[0];
    const float* k = (const float*)d_in[1];
    const float* v = (const float*)d_in[2];
    float* o = (float*)d_out;

    const size_t QBF_BYTES = (size_t)B_ * S_ * D_ * 2;              // 4 MB
    const size_t KV_BYTES  = (size_t)B_ * NT_ * BLOB_SHORTS * 2;    // 8 MB
    const size_t PREFIX    = QBF_BYTES + KV_BYTES;                  // 12 MB
    const size_t O_FLOATS  = (size_t)B_ * NT_ * BM * D_;
    const size_t ML_FLOATS = (size_t)B_ * NT_ * BM * 2;
    const size_t PER_R     = (O_FLOATS + ML_FLOATS) * sizeof(float);

    char* ws = (char*)d_ws;
    short* Qbf = (short*)ws;
    short* KV  = (short*)(ws + QBF_BYTES);

    int R = 0;
    if (ws_size > PREFIX) {
        R = (int)((ws_size - PREFIX) / PER_R);
        if (R > RMAX) R = RMAX;
    }

    prep<<<dim3(2048), 256, 0, stream>>>(q, k, v, Qbf, KV);

    if (R >= 1) {
        float* Op = (float*)(ws + PREFIX);
        float* Ml = Op + (size_t)R * O_FLOATS;
        fa_fwd<true><<<dim3(B_ * NT_ * R), 256, 0, stream>>>(Qbf, KV, nullptr, Op, Ml, R);
        switch (R) {
            case 1: fa_merge<1><<<dim3(B_ * NT_ * 8), 256, 0, stream>>>(Op, Ml, o); break;
            case 2: fa_merge<2><<<dim3(B_ * NT_ * 8), 256, 0, stream>>>(Op, Ml, o); break;
            case 3: fa_merge<3><<<dim3(B_ * NT_ * 8), 256, 0, stream>>>(Op, Ml, o); break;
            default: fa_merge<4><<<dim3(B_ * NT_ * 8), 256, 0, stream>>>(Op, Ml, o); break;
        }
    } else {
        fa_fwd<false><<<dim3(B_ * NT_), 256, 0, stream>>>(Qbf, KV, o, nullptr, nullptr, 1);
    }
}

// Round 7
// 123.494 us; speedup vs baseline: 1.5826x; 1.5826x over previous
//
#include <hip/hip_runtime.h>

// Causal single-head attention, B=4, S=4096, D=128, fp32 in/out.
// R7 (= R6 + NaN fix): finite mask value (-1e30) instead of -inf. With
// BM=128 a boundary k-tile can be fully masked for half the q-rows; if a
// split chunk starts there, -inf-(-inf)=NaN poisoned m/l/acc. All-finite
// arithmetic self-recovers (al=0 rescale) and merge weights underflow to 0.

#define B_   4
#define S_   4096
#define D_   128
#define BN   64
#define NT_  64             // 64-key blobs per batch (prep granularity)
#define QT_  32             // q-tiles per batch (BM=128)
#define RMAX 4
#define BLOB_SHORTS 16384   // 32 KB per (b,kt): [K img 16KB][V^T img 16KB]
#define MASKVAL (-1.0e30f)

typedef __attribute__((ext_vector_type(8))) short bf16x8;
typedef __attribute__((ext_vector_type(4))) float f32x4;

__device__ __forceinline__ short f2bf(float x) {
    unsigned u = __builtin_bit_cast(unsigned, x);
    unsigned r = (u + 0x7fffu + ((u >> 16) & 1u)) >> 16;
    return (short)r;
}
__device__ __forceinline__ float ex2(float x) { return __builtin_amdgcn_exp2f(x); }
__device__ __forceinline__ unsigned pkbf(float lo, float hi) {
    return (unsigned)(unsigned short)f2bf(lo) | ((unsigned)(unsigned short)f2bf(hi) << 16);
}
__device__ __forceinline__ void gl_lds16(const short* g, short* l) {
    __builtin_amdgcn_global_load_lds(
        (const __attribute__((address_space(1))) unsigned int*)g,
        (__attribute__((address_space(3))) unsigned int*)l, 16, 0, 0);
}

// ---------------- prep: 2048 blocks ---------------------------------------
// K image: row n (64) x 16 granules of 8 bf16; source granule G at
//   p = (G&8) | ((G&7) ^ (n&7)).
// V image: row d (128) x 8 granules; source granule G (= k-octet) at
//   p = G ^ (d&7); granule holds V[kt*64+G*8+i][d], i=0..7.
__global__ __launch_bounds__(256) void prep(const float* __restrict__ Qg,
                                            const float* __restrict__ Kg,
                                            const float* __restrict__ Vg,
                                            short* __restrict__ Qbf,
                                            short* __restrict__ KV)
{
    __shared__ short vt[64][40];
    const int id  = blockIdx.x;
    const int tid = threadIdx.x;
    const float SC = 0.12751740f;   // log2(e)/sqrt(128)

    if (id < 1024) {
        const int b = id & 3, tile = (id >> 2) & 63, q4 = id >> 8;
        const int n = q4 * 16 + (tid >> 4);
        const int G = tid & 15;
        const size_t rowoff = ((size_t)b * S_ + (size_t)tile * 64 + n) * D_ + G * 8;
        short* blob = KV + (size_t)(b * NT_ + tile) * BLOB_SHORTS;
        {
            float4 a = *reinterpret_cast<const float4*>(Qg + rowoff);
            float4 c = *reinterpret_cast<const float4*>(Qg + rowoff + 4);
            bf16x8 v;
            v[0] = f2bf(a.x * SC); v[1] = f2bf(a.y * SC); v[2] = f2bf(a.z * SC); v[3] = f2bf(a.w * SC);
            v[4] = f2bf(c.x * SC); v[5] = f2bf(c.y * SC); v[6] = f2bf(c.z * SC); v[7] = f2bf(c.w * SC);
            *reinterpret_cast<bf16x8*>(Qbf + rowoff) = v;
        }
        {
            float4 a = *reinterpret_cast<const float4*>(Kg + rowoff);
            float4 c = *reinterpret_cast<const float4*>(Kg + rowoff + 4);
            bf16x8 v;
            v[0] = f2bf(a.x); v[1] = f2bf(a.y); v[2] = f2bf(a.z); v[3] = f2bf(a.w);
            v[4] = f2bf(c.x); v[5] = f2bf(c.y); v[6] = f2bf(c.z); v[7] = f2bf(c.w);
            const int p = (G & 8) | ((G & 7) ^ (n & 7));
            *reinterpret_cast<bf16x8*>(blob + n * 128 + p * 8) = v;
        }
    } else {
        const int u = id - 1024;
        const int b = u & 3, tile = (u >> 2) & 63, dq = u >> 8;
        short* blob = KV + (size_t)(b * NT_ + tile) * BLOB_SHORTS;
        {
            const int n = tid >> 2, c8 = tid & 3;
            const size_t off = ((size_t)b * S_ + (size_t)tile * 64 + n) * D_ + dq * 32 + c8 * 8;
            float4 a = *reinterpret_cast<const float4*>(Vg + off);
            float4 c = *reinterpret_cast<const float4*>(Vg + off + 4);
            bf16x8 v;
            v[0] = f2bf(a.x); v[1] = f2bf(a.y); v[2] = f2bf(a.z); v[3] = f2bf(a.w);
            v[4] = f2bf(c.x); v[5] = f2bf(c.y); v[6] = f2bf(c.z); v[7] = f2bf(c.w);
            *reinterpret_cast<bf16x8*>(&vt[n][c8 * 8]) = v;
        }
        __syncthreads();
        {
            const int dl = tid >> 3, G = tid & 7;
            const int d  = dq * 32 + dl;
            bf16x8 g;
#pragma unroll
            for (int i = 0; i < 8; ++i) g[i] = vt[G * 8 + i][dl];
            const int p = G ^ (d & 7);
            *reinterpret_cast<bf16x8*>(blob + 8192 + d * 64 + p * 8) = g;
        }
    }
}

// ---------------- fa_fwd: 512 threads, BM=128 ------------------------------
template<bool SPLIT>
__global__ __launch_bounds__(512, 4) void fa_fwd(const short* __restrict__ Qbf,
                                                 const short* __restrict__ KV,
                                                 float* __restrict__ Og,
                                                 float* __restrict__ Op,
                                                 float* __restrict__ Ml,
                                                 int R)
{
    __shared__ short lkv[2][BLOB_SHORTS];   // 64 KB double buffer

    const int tid  = threadIdx.x;
    const int wv   = tid >> 6;      // 0..7: q-rows [wv*16, wv*16+16)
    const int lane = tid & 63;
    const int m    = lane & 15;
    const int quad = lane >> 4;
    const int m7   = m & 7;

    int batch, t, lo, hi, chunk_id;
    {
        const int id = blockIdx.x;
        batch = id & 3;
        if (SPLIT) {
            int u = id >> 2;
            int tt = u / R;
            int r  = u - tt * R;
            t  = QT_ - 1 - tt;                 // heavy q-tiles dispatch first
            const int nk = 2 * t + 2;          // k-tiles needed by this q-tile
            lo = r * nk / R;
            hi = (r + 1) * nk / R;
            chunk_id = (batch * QT_ + t) * R + r;
            if (lo >= hi) return;              // block-uniform, before barriers
        } else {
            t  = QT_ - 1 - (id >> 2);
            lo = 0; hi = 2 * t + 2; chunk_id = 0;
        }
    }

    // Q fragment (pre-scaled bf16): q-row = t*128 + wv*16 + m
    bf16x8 qf[4];
    {
        const short* qp = Qbf + ((size_t)batch * S_ + (size_t)t * 128 + wv * 16 + m) * D_ + quad * 8;
#pragma unroll
        for (int c = 0; c < 4; ++c)
            qf[c] = *reinterpret_cast<const bf16x8*>(qp + c * 32);
    }

    f32x4 acc[8];
#pragma unroll
    for (int i = 0; i < 8; ++i) acc[i] = (f32x4){0.f, 0.f, 0.f, 0.f};
    float mrun = MASKVAL, lrun = 0.f;   // per-lane: q-row = m (finite init!)

    const size_t tilebase = (size_t)batch * NT_ * BLOB_SHORTS;
    // 512 threads x 4 x 16B = 32 KB blob
#define STAGE(KT, BUF) do {                                                   \
        const short* g_ = KV + tilebase + (size_t)(KT) * BLOB_SHORTS + tid * 8;\
        short* l_ = (BUF) + tid * 8;                                          \
        _Pragma("unroll")                                                     \
        for (int c_ = 0; c_ < 4; ++c_)                                        \
            gl_lds16(g_ + c_ * 4096, l_ + c_ * 4096);                         \
    } while (0)

    STAGE(lo, lkv[0]);

    for (int kt = lo; kt < hi; ++kt) {
        const short* cur = lkv[(kt - lo) & 1];
        short* nxt = lkv[(kt - lo + 1) & 1];
        __syncthreads();   // vmcnt(0) drain: cur complete; prev reads of nxt done
        if (kt + 1 < hi) STAGE(kt + 1, nxt);   // in flight during compute

        const short* lk = cur;
        const short* lv = cur + 8192;

        // ---- S^T = K * Q^T : st[nt] rows k-local=quad*4+r, col q=m
        f32x4 st[4];
#pragma unroll
        for (int nt = 0; nt < 4; ++nt) st[nt] = (f32x4){0.f, 0.f, 0.f, 0.f};
#pragma unroll
        for (int c = 0; c < 4; ++c) {
            const int p = ((c >> 1) * 8) | ((((c & 1) * 4) | quad) ^ m7);
#pragma unroll
            for (int nt = 0; nt < 4; ++nt) {
                bf16x8 kf = *reinterpret_cast<const bf16x8*>(lk + nt * 2048 + m * 128 + p * 8);
                st[nt] = __builtin_amdgcn_mfma_f32_16x16x32_bf16(kf, qf[c], st[nt], 0, 0, 0);
            }
        }

        // ---- causal mask: only the last two k-tiles of this q-tile need it
        if (kt >= 2 * t) {
            const int kbase = (kt - 2 * t) * 64;   // 0 or 64
            const int qloc  = wv * 16 + m;
#pragma unroll
            for (int nt = 0; nt < 4; ++nt)
#pragma unroll
                for (int r = 0; r < 4; ++r)
                    if (kbase + nt * 16 + quad * 4 + r > qloc) st[nt][r] = MASKVAL;
        }

        // ---- online softmax: row = m, per-lane + 2 shfl (all-finite math)
        float mx = MASKVAL;
#pragma unroll
        for (int nt = 0; nt < 4; ++nt)
#pragma unroll
            for (int r = 0; r < 4; ++r) mx = fmaxf(mx, st[nt][r]);
        mx = fmaxf(mx, __shfl_xor(mx, 16));
        mx = fmaxf(mx, __shfl_xor(mx, 32));
        const float mnew = fmaxf(mrun, mx);
        const float al   = ex2(mrun - mnew);   // finite-finite: never NaN
        mrun = mnew;
        float sum = 0.f;
#pragma unroll
        for (int nt = 0; nt < 4; ++nt)
#pragma unroll
            for (int r = 0; r < 4; ++r) {
                float pv = ex2(st[nt][r] - mnew);
                st[nt][r] = pv;
                sum += pv;
            }
        sum += __shfl_xor(sum, 16);
        sum += __shfl_xor(sum, 32);
        lrun = lrun * al + sum;
#pragma unroll
        for (int r = 0; r < 4; ++r) {
            float alq = __shfl(al, quad * 4 + r);
#pragma unroll
            for (int ct = 0; ct < 8; ++ct) acc[ct][r] *= alq;
        }

        // ---- PV with in-register P transpose (per-ks pk: short live range)
        const int srcA = ((quad & 1) << 5) + m;
        const int srcB = srcA + 16;
        const bool loq = quad < 2;
#pragma unroll
        for (int ks = 0; ks < 2; ++ks) {
            unsigned pk0 = pkbf(st[2 * ks][0],     st[2 * ks][1]);
            unsigned pk1 = pkbf(st[2 * ks][2],     st[2 * ks][3]);
            unsigned pk2 = pkbf(st[2 * ks + 1][0], st[2 * ks + 1][1]);
            unsigned pk3 = pkbf(st[2 * ks + 1][2], st[2 * ks + 1][3]);
            unsigned w0a = __shfl((int)pk0, srcA);
            unsigned w0b = __shfl((int)pk2, srcA);
            unsigned w1a = __shfl((int)pk1, srcA);
            unsigned w1b = __shfl((int)pk3, srcA);
            unsigned w2a = __shfl((int)pk0, srcB);
            unsigned w2b = __shfl((int)pk2, srcB);
            unsigned w3a = __shfl((int)pk1, srcB);
            unsigned w3b = __shfl((int)pk3, srcB);
            int4 wi;
            wi.x = (int)(loq ? w0a : w0b);
            wi.y = (int)(loq ? w1a : w1b);
            wi.z = (int)(loq ? w2a : w2b);
            wi.w = (int)(loq ? w3a : w3b);
            bf16x8 pf = __builtin_bit_cast(bf16x8, wi);
            const int p = (ks * 4 + quad) ^ m7;
#pragma unroll
            for (int ct = 0; ct < 8; ++ct) {
                bf16x8 vf = *reinterpret_cast<const bf16x8*>(lv + ct * 1024 + m * 64 + p * 8);
                acc[ct] = __builtin_amdgcn_mfma_f32_16x16x32_bf16(pf, vf, acc[ct], 0, 0, 0);
            }
        }
    }
#undef STAGE

    const int row0 = wv * 16 + quad * 4;
    if (SPLIT) {
        float* ob = Op + (size_t)chunk_id * (128 * D_);
#pragma unroll
        for (int r = 0; r < 4; ++r)
#pragma unroll
            for (int ct = 0; ct < 8; ++ct)
                ob[(row0 + r) * D_ + ct * 16 + m] = acc[ct][r];
        if (lane < 16) {
            float* mlb = Ml + (size_t)chunk_id * (128 * 2) + (wv * 16 + lane) * 2;
            mlb[0] = mrun;
            mlb[1] = lrun;
        }
    } else {
        const float inv = 1.0f / lrun;
        const size_t obase = ((size_t)batch * S_ + (size_t)t * 128 + row0) * D_;
#pragma unroll
        for (int r = 0; r < 4; ++r) {
            float invq = __shfl(inv, quad * 4 + r);
#pragma unroll
            for (int ct = 0; ct < 8; ++ct)
                Og[obase + (size_t)r * D_ + ct * 16 + m] = acc[ct][r] * invq;
        }
    }
}

// ---------------- merge: 2048 blocks, 8 rows each --------------------------
template<int RR>
__global__ __launch_bounds__(256) void fa_merge(const float* __restrict__ Op,
                                                const float* __restrict__ Ml,
                                                float* __restrict__ Og)
{
    const int x   = blockIdx.x;
    const int btq = x >> 4;                 // b*QT_ + t
    const int oct = x & 15;
    const int t   = btq & (QT_ - 1);
    const int nk  = 2 * t + 2;
    const int row = oct * 8 + (threadIdx.x >> 5);   // 0..127
    const int cg  = threadIdx.x & 31;               // 4 floats per thread
    const size_t cbase = (size_t)btq * RR;

    float mg = MASKVAL;
#pragma unroll
    for (int r = 0; r < RR; ++r) {
        int lo = r * nk / RR, hi = (r + 1) * nk / RR;
        if (lo < hi) mg = fmaxf(mg, Ml[(cbase + r) * (128 * 2) + row * 2]);
    }
    float l = 0.f;
    f32x4 a = (f32x4){0.f, 0.f, 0.f, 0.f};
#pragma unroll
    for (int r = 0; r < RR; ++r) {
        int lo = r * nk / RR, hi = (r + 1) * nk / RR;
        if (lo >= hi) continue;
        float mr = Ml[(cbase + r) * (128 * 2) + row * 2];
        float lr = Ml[(cbase + r) * (128 * 2) + row * 2 + 1];
        float w  = ex2(mr - mg);   // fully-masked chunk: underflows to 0
        l += lr * w;
        a += w * *reinterpret_cast<const f32x4*>(Op + (cbase + r) * (128 * D_) + row * D_ + cg * 4);
    }
    *reinterpret_cast<f32x4*>(Og + (size_t)btq * (128 * D_) + row * D_ + cg * 4) = a * (1.0f / l);
}

extern "C" void kernel_launch(void* const* d_in, const int* in_sizes, int n_in,
                              void* d_out, int out_size, void* d_ws, size_t ws_size,
                              hipStream_t stream) {
    const float* q = (const float*)d_in[0];
    const float* k = (const float*)d_in[1];
    const float* v = (const float*)d_in[2];
    float* o = (float*)d_out;

    const size_t QBF_BYTES = (size_t)B_ * S_ * D_ * 2;              // 4 MB
    const size_t KV_BYTES  = (size_t)B_ * NT_ * BLOB_SHORTS * 2;    // 8 MB
    const size_t PREFIX    = QBF_BYTES + KV_BYTES;                  // 12 MB
    const size_t O_FLOATS  = (size_t)B_ * QT_ * 128 * D_;           // per R-unit
    const size_t ML_FLOATS = (size_t)B_ * QT_ * 128 * 2;
    const size_t PER_R     = (O_FLOATS + ML_FLOATS) * sizeof(float);

    char* ws = (char*)d_ws;
    short* Qbf = (short*)ws;
    short* KV  = (short*)(ws + QBF_BYTES);

    int R = 0;
    if (ws_size > PREFIX) {
        R = (int)((ws_size - PREFIX) / PER_R);
        if (R > RMAX) R = RMAX;
    }

    prep<<<dim3(2048), 256, 0, stream>>>(q, k, v, Qbf, KV);

    if (R >= 1) {
        float* Op = (float*)(ws + PREFIX);
        float* Ml = Op + (size_t)R * O_FLOATS;
        fa_fwd<true><<<dim3(B_ * QT_ * R), 512, 0, stream>>>(Qbf, KV, nullptr, Op, Ml, R);
        switch (R) {
            case 1: fa_merge<1><<<dim3(B_ * QT_ * 16), 256, 0, stream>>>(Op, Ml, o); break;
            case 2: fa_merge<2><<<dim3(B_ * QT_ * 16), 256, 0, stream>>>(Op, Ml, o); break;
            case 3: fa_merge<3><<<dim3(B_ * QT_ * 16), 256, 0, stream>>>(Op, Ml, o); break;
            default: fa_merge<4><<<dim3(B_ * QT_ * 16), 256, 0, stream>>>(Op, Ml, o); break;
        }
    } else {
        fa_fwd<false><<<dim3(B_ * QT_), 512, 0, stream>>>(Qbf, KV, o, nullptr, nullptr, 1);
    }
}